// Round 1
// baseline (96.899 us; speedup 1.0000x reference)
//
#include <hip/hip_runtime.h>
#include <math.h>

#define BB 8
#define HH 384
#define WW 1280
#define LHh (HH/4)   // 96
#define LWw (WW/4)   // 320

// One thread per low-res cell (4x4 output tile). SCALE=2 paths hand-unrolled.
// Block-local coords: r=mm+2, c=nn+2, center at (2,2).
__global__ __launch_bounds__(256) void sno_kernel(
    const float* __restrict__ depthlow,   // B,1,LH,LW
    const float* __restrict__ ang,        // B,2,H,W
    const float* __restrict__ intr,       // B,3,3
    float* __restrict__ out)              // B,1,H,W
{
    int tid = blockIdx.x * blockDim.x + threadIdx.x;
    const int nblk = BB * LHh * LWw;
    if (tid >= nblk) return;
    int cx = tid % LWw;
    int t2 = tid / LWw;
    int cy = t2 % LHh;
    int b  = t2 / LHh;

    const float fx = intr[b*9 + 0];
    const float bx = intr[b*9 + 2];
    const float fy = intr[b*9 + 4];
    const float by = intr[b*9 + 5];

    // per-row / per-col geometry
    float a1[4], v1[4], v2[4];
    float u1[4], b1v[4], b2v[4];
#pragma unroll
    for (int r = 0; r < 4; ++r) {
        float y = (float)(cy*4 + r);
        float t = (y - by) / fy;
        a1[r] = t*t + 1.0f;
        v1[r] = -t;
        v2[r] = -((y + 1.0f) - by) / fy;
    }
#pragma unroll
    for (int c = 0; c < 4; ++c) {
        float x = (float)(cx*4 + c);
        float t = (x - bx) / fx;
        u1[c]  = t*t + 1.0f;
        b1v[c] = -t;
        b2v[c] = -((x + 1.0f) - bx) / fx;
    }

    const int x0 = cx * 4;
    const size_t angbase = (size_t)b * 2 * HH * WW;

    // load ang ch0 (rows 0..3) and ch1 (rows 0..2) as float4
    float4 ah[4], av[3];
#pragma unroll
    for (int r = 0; r < 4; ++r) {
        int y = cy*4 + r;
        ah[r] = *(const float4*)(ang + angbase + (size_t)y * WW + x0);
    }
#pragma unroll
    for (int r = 0; r < 3; ++r) {
        int y = cy*4 + r;
        av[r] = *(const float4*)(ang + angbase + (size_t)HH * WW + (size_t)y * WW + x0);
    }

    const float pm = 1e-6f;

    // LH[r][c] : logh at (y=cy*4+r, x=cx*4+c), c in 0..2
    float LHt[4][3];
#pragma unroll
    for (int r = 0; r < 4; ++r) {
        const float* ap = (const float*)&ah[r];
#pragma unroll
        for (int c = 0; c < 3; ++c) {
            float s = sinf(ap[c]);
            float cc = cosf(ap[c]);
            float a3 = s, b3 = -cc;
            float t1 = a3 * b1v[c] - a1[r] * b3;
            float t2v = a3 * b2v[c] - a1[r] * b3;
            float l = logf(fmaxf(fabsf(t1), pm)) - logf(fmaxf(fabsf(t2v), pm));
            LHt[r][c] = fminf(fmaxf(l, -10.0f), 10.0f);
        }
    }

    // LV[r][c] : logv at (y=cy*4+r, x=cx*4+c), r in 0..2
    float LVt[3][4];
#pragma unroll
    for (int r = 0; r < 3; ++r) {
        const float* ap = (const float*)&av[r];
#pragma unroll
        for (int c = 0; c < 4; ++c) {
            float s = sinf(ap[c]);
            float cc = cosf(ap[c]);
            float u3 = s, v3 = -cc;
            float t1 = u3 * v1[r] - u1[c] * v3;
            float t2v = u3 * v2[r] - u1[c] * v3;
            float l = logf(fmaxf(fabsf(t1), pm)) - logf(fmaxf(fabsf(t2v), pm));
            LVt[r][c] = fminf(fmaxf(l, -10.0f), 10.0f);
        }
    }

    // propagation DAG (hand-unrolled _build_paths(2), verified order)
    float D[4][4];
    D[2][2] = logf(depthlow[(size_t)b*LHh*LWw + (size_t)cy*LWw + cx]);
    D[2][1] = D[2][2] - LHt[2][1];
    D[2][3] = D[2][2] + LHt[2][2];
    D[2][0] = D[2][1] - LHt[2][0];
    D[1][2] = D[2][2] - LVt[1][2];
    D[1][1] = 0.5f*(D[1][2] - LHt[1][1] + D[2][1] - LVt[1][1]);
    D[1][3] = 0.5f*(D[1][2] + LHt[1][2] + D[2][3] - LVt[1][3]);
    D[1][0] = 0.5f*(D[1][1] - LHt[1][0] + D[2][0] - LVt[1][0]);
    D[3][2] = D[2][2] + LVt[2][2];
    D[3][1] = 0.5f*(D[3][2] - LHt[3][1] + D[2][1] + LVt[2][1]);
    D[3][3] = 0.5f*(D[3][2] + LHt[3][2] + D[2][3] + LVt[2][3]);
    D[3][0] = 0.5f*(D[3][1] - LHt[3][0] + D[2][0] + LVt[2][0]);
    D[0][2] = D[1][2] - LVt[0][2];
    D[0][1] = 0.5f*(D[0][2] - LHt[0][1] + D[1][1] - LVt[0][1]);
    D[0][3] = 0.5f*(D[0][2] + LHt[0][2] + D[1][3] - LVt[0][3]);
    D[0][0] = 0.5f*(D[0][1] - LHt[0][0] + D[1][0] - LVt[0][0]);

    // write exp(D) as 4 coalesced float4 rows
    const size_t obase = (size_t)b * HH * WW;
#pragma unroll
    for (int r = 0; r < 4; ++r) {
        int y = cy*4 + r;
        float4 o;
        o.x = expf(D[r][0]);
        o.y = expf(D[r][1]);
        o.z = expf(D[r][2]);
        o.w = expf(D[r][3]);
        *(float4*)(out + obase + (size_t)y * WW + x0) = o;
    }
}

extern "C" void kernel_launch(void* const* d_in, const int* in_sizes, int n_in,
                              void* d_out, int out_size, void* d_ws, size_t ws_size,
                              hipStream_t stream) {
    const float* depthlow = (const float*)d_in[0];
    const float* ang      = (const float*)d_in[1];
    const float* intr     = (const float*)d_in[2];
    float* out = (float*)d_out;

    const int nblk = BB * LHh * LWw;          // 245760
    dim3 grid((nblk + 255) / 256), block(256);
    hipLaunchKernelGGL(sno_kernel, grid, block, 0, stream,
                       depthlow, ang, intr, out);
}

// Round 2
// 89.548 us; speedup vs baseline: 1.0821x; 1.0821x over previous
//
#include <hip/hip_runtime.h>
#include <math.h>

#define BB 8
#define HH 384
#define WW 1280
#define LHh (HH/4)   // 96
#define LWw (WW/4)   // 320

// One thread per low-res cell (4x4 output tile). SCALE=2 paths hand-unrolled.
// R1: hardware transcendentals (__sinf/__cosf/__logf/__expf -> v_sin/v_cos/
// v_log/v_exp), reciprocal hoisting, CSE of a1*cos term.
__global__ __launch_bounds__(256) void sno_kernel(
    const float* __restrict__ depthlow,   // B,1,LH,LW
    const float* __restrict__ ang,        // B,2,H,W
    const float* __restrict__ intr,       // B,3,3
    float* __restrict__ out)              // B,1,H,W
{
    int tid = blockIdx.x * blockDim.x + threadIdx.x;
    const int nblk = BB * LHh * LWw;
    if (tid >= nblk) return;
    int cx = tid % LWw;
    int t2 = tid / LWw;
    int cy = t2 % LHh;
    int b  = t2 / LHh;

    const float fx = intr[b*9 + 0];
    const float bx = intr[b*9 + 2];
    const float fy = intr[b*9 + 4];
    const float by = intr[b*9 + 5];
    const float rfx = 1.0f / fx;
    const float rfy = 1.0f / fy;

    // per-row / per-col geometry
    float a1[4], v1[4], v2[4];
    float u1[4], b1v[4], b2v[4];
#pragma unroll
    for (int r = 0; r < 4; ++r) {
        float y = (float)(cy*4 + r);
        float t = (y - by) * rfy;
        a1[r] = fmaf(t, t, 1.0f);
        v1[r] = -t;
        v2[r] = -((y + 1.0f) - by) * rfy;
    }
#pragma unroll
    for (int c = 0; c < 4; ++c) {
        float x = (float)(cx*4 + c);
        float t = (x - bx) * rfx;
        u1[c]  = fmaf(t, t, 1.0f);
        b1v[c] = -t;
        b2v[c] = -((x + 1.0f) - bx) * rfx;
    }

    const int x0 = cx * 4;
    const size_t angbase = (size_t)b * 2 * HH * WW;

    // load ang ch0 (rows 0..3) and ch1 (rows 0..2) as float4
    float4 ah[4], av[3];
#pragma unroll
    for (int r = 0; r < 4; ++r) {
        int y = cy*4 + r;
        ah[r] = *(const float4*)(ang + angbase + (size_t)y * WW + x0);
    }
#pragma unroll
    for (int r = 0; r < 3; ++r) {
        int y = cy*4 + r;
        av[r] = *(const float4*)(ang + angbase + (size_t)HH * WW + (size_t)y * WW + x0);
    }

    const float pm = 1e-6f;

    // LH[r][c] : logh at (y=cy*4+r, x=cx*4+c), c in 0..2
    // t1 = a3*b1 - a1*b3 with a3=sin, b3=-cos  ->  t1 = s*b1 + a1*cos
    float LHt[4][3];
#pragma unroll
    for (int r = 0; r < 4; ++r) {
        const float* ap = (const float*)&ah[r];
#pragma unroll
        for (int c = 0; c < 3; ++c) {
            float s  = __sinf(ap[c]);
            float cc = __cosf(ap[c]);
            float q  = a1[r] * cc;
            float t1  = fmaf(s, b1v[c], q);
            float t2v = fmaf(s, b2v[c], q);
            float l = __logf(fmaxf(fabsf(t1), pm)) - __logf(fmaxf(fabsf(t2v), pm));
            LHt[r][c] = fminf(fmaxf(l, -10.0f), 10.0f);
        }
    }

    // LV[r][c] : logv at (y=cy*4+r, x=cx*4+c), r in 0..2
    float LVt[3][4];
#pragma unroll
    for (int r = 0; r < 3; ++r) {
        const float* ap = (const float*)&av[r];
#pragma unroll
        for (int c = 0; c < 4; ++c) {
            float s  = __sinf(ap[c]);
            float cc = __cosf(ap[c]);
            float q  = u1[c] * cc;
            float t1  = fmaf(s, v1[r], q);
            float t2v = fmaf(s, v2[r], q);
            float l = __logf(fmaxf(fabsf(t1), pm)) - __logf(fmaxf(fabsf(t2v), pm));
            LVt[r][c] = fminf(fmaxf(l, -10.0f), 10.0f);
        }
    }

    // propagation DAG (hand-unrolled _build_paths(2), verified order)
    float D[4][4];
    D[2][2] = __logf(depthlow[(size_t)b*LHh*LWw + (size_t)cy*LWw + cx]);
    D[2][1] = D[2][2] - LHt[2][1];
    D[2][3] = D[2][2] + LHt[2][2];
    D[2][0] = D[2][1] - LHt[2][0];
    D[1][2] = D[2][2] - LVt[1][2];
    D[1][1] = 0.5f*(D[1][2] - LHt[1][1] + D[2][1] - LVt[1][1]);
    D[1][3] = 0.5f*(D[1][2] + LHt[1][2] + D[2][3] - LVt[1][3]);
    D[1][0] = 0.5f*(D[1][1] - LHt[1][0] + D[2][0] - LVt[1][0]);
    D[3][2] = D[2][2] + LVt[2][2];
    D[3][1] = 0.5f*(D[3][2] - LHt[3][1] + D[2][1] + LVt[2][1]);
    D[3][3] = 0.5f*(D[3][2] + LHt[3][2] + D[2][3] + LVt[2][3]);
    D[3][0] = 0.5f*(D[3][1] - LHt[3][0] + D[2][0] + LVt[2][0]);
    D[0][2] = D[1][2] - LVt[0][2];
    D[0][1] = 0.5f*(D[0][2] - LHt[0][1] + D[1][1] - LVt[0][1]);
    D[0][3] = 0.5f*(D[0][2] + LHt[0][2] + D[1][3] - LVt[0][3]);
    D[0][0] = 0.5f*(D[0][1] - LHt[0][0] + D[1][0] - LVt[0][0]);

    // write exp(D) as 4 coalesced float4 rows
    const size_t obase = (size_t)b * HH * WW;
#pragma unroll
    for (int r = 0; r < 4; ++r) {
        int y = cy*4 + r;
        float4 o;
        o.x = __expf(D[r][0]);
        o.y = __expf(D[r][1]);
        o.z = __expf(D[r][2]);
        o.w = __expf(D[r][3]);
        *(float4*)(out + obase + (size_t)y * WW + x0) = o;
    }
}

extern "C" void kernel_launch(void* const* d_in, const int* in_sizes, int n_in,
                              void* d_out, int out_size, void* d_ws, size_t ws_size,
                              hipStream_t stream) {
    const float* depthlow = (const float*)d_in[0];
    const float* ang      = (const float*)d_in[1];
    const float* intr     = (const float*)d_in[2];
    float* out = (float*)d_out;

    const int nblk = BB * LHh * LWw;          // 245760
    dim3 grid((nblk + 255) / 256), block(256);
    hipLaunchKernelGGL(sno_kernel, grid, block, 0, stream,
                       depthlow, ang, intr, out);
}